// Round 2
// baseline (513.660 us; speedup 1.0000x reference)
//
#include <hip/hip_runtime.h>

#define NN 512
#define SCALE 0.35355339059327373f  /* dk^-0.5, dk=8 */

__global__ __launch_bounds__(64) void qkv_proj(const float* __restrict__ nin,
                                               const float* __restrict__ Wqkv,
                                               float* __restrict__ qkv) {
    const int r = blockIdx.x;   // b*512+n
    const int j = threadIdx.x;  // 0..63
    const float* nr = nin + (size_t)r * 64;
    float a0 = 0.f, a1 = 0.f, a2 = 0.f;
#pragma unroll
    for (int d = 0; d < 64; ++d) {
        const float nv = nr[d];                 // block-uniform -> s_load
        const float* wr = Wqkv + d * 192;
        a0 = fmaf(nv, wr[j], a0);
        a1 = fmaf(nv, wr[64 + j], a1);
        a2 = fmaf(nv, wr[128 + j], a2);
    }
    float* o = qkv + (size_t)r * 192;
    o[j] = a0; o[64 + j] = a1; o[128 + j] = a2;
}

__global__ __launch_bounds__(256, 2) void edge_fused(
    const float* __restrict__ e,
    const float* __restrict__ qkv,
    const float* __restrict__ We,   // (64,8)
    const float* __restrict__ Wg,   // (64,8)
    const float* __restrict__ Oe,   // (8,64)
    const float* __restrict__ On,   // (64,64)
    float* __restrict__ n_out,      // (B,N,64)
    float* __restrict__ e_out)      // (B,N,N,64)
{
    __shared__ float Es[NN * 8];      // pre-softmax scores _E[m][h], f32
    __shared__ float est[64 * 65];    // e tile, stride-65 pad
    __shared__ float kst[64 * 65];    // K tile, stride-65 pad
    __shared__ float Esum[64 * 17];   // cross-wave partial sums (ee|ge)
    __shared__ float mx[8], invden[8], centr[8], gsum_sh[8];

    const int t = threadIdx.x;
    const int w = t >> 6;
    const int l = t & 63;
    const int wq = __builtin_amdgcn_readfirstlane(w);  // wave-uniform quarter id
    const int bn = blockIdx.x;
    const int b = bn >> 9;

    const float* Q = qkv + (size_t)bn * 192;
    const int r_ = t >> 2;
    const int dq_ = (t & 3) * 16;
    const float* e_base = e + (size_t)bn * 512 * 64;

    float gs0 = 0.f, gs1 = 0.f;

    for (int tile = 0; tile < 8; ++tile) {
        const int m0 = tile * 64;
        __syncthreads();
        // ---- stage e-tile + K-tile, zero Esum ----
        {
            const float* es_ = e_base + (size_t)(m0 + r_) * 64 + dq_;
            const float* ks_ = qkv + (size_t)(b * NN + m0 + r_) * 192 + 64 + dq_;
            float* ed = est + r_ * 65 + dq_;
            float* kd = kst + r_ * 65 + dq_;
#pragma unroll
            for (int u = 0; u < 4; ++u) {
                const float4 v = reinterpret_cast<const float4*>(es_)[u];
                ed[u * 4 + 0] = v.x; ed[u * 4 + 1] = v.y; ed[u * 4 + 2] = v.z; ed[u * 4 + 3] = v.w;
                const float4 kv = reinterpret_cast<const float4*>(ks_)[u];
                kd[u * 4 + 0] = kv.x; kd[u * 4 + 1] = kv.y; kd[u * 4 + 2] = kv.z; kd[u * 4 + 3] = kv.w;
            }
            for (int i = t; i < 64 * 17; i += 256) Esum[i] = 0.f;
        }
        __syncthreads();
        // ---- compute: lane = m, wave = d-quarter (weights/Q wave-uniform -> s_load) ----
        {
            const float* er = est + l * 65 + wq * 16;
            const float* kr = kst + l * 65 + wq * 16;
            float ee[8], gg[8];
#pragma unroll
            for (int j = 0; j < 8; ++j) { ee[j] = 0.f; gg[j] = 0.f; }
            float a0 = 0.f, a1 = 0.f;
#pragma unroll
            for (int dd = 0; dd < 16; ++dd) {
                const int d = wq * 16 + dd;
                const float ev = er[dd];
                const float kv = kr[dd];
                const float qv = Q[d];
                if (dd < 8) a0 = fmaf(kv, qv, a0);
                else        a1 = fmaf(kv, qv, a1);
                const float* wer = We + d * 8;
                const float* wgr = Wg + d * 8;
#pragma unroll
                for (int j = 0; j < 8; ++j) {
                    ee[j] = fmaf(ev, wer[j], ee[j]);
                    gg[j] = fmaf(ev, wgr[j], gg[j]);
                }
            }
            float* Em = Esum + l * 17;
#pragma unroll
            for (int j = 0; j < 8; ++j) {
                atomicAdd(Em + j, ee[j]);
                atomicAdd(Em + 8 + j, gg[j]);
            }
            __syncthreads();
            // finalize: wave w owns heads 2w, 2w+1 (its d-quarter covers them fully)
            const int h0 = 2 * wq;
            const float E0 = fminf(fmaxf(a0 * SCALE, -5.f), 5.f) + Em[h0];
            const float E1 = fminf(fmaxf(a1 * SCALE, -5.f), 5.f) + Em[h0 + 1];
            const int m = m0 + l;
            Es[m * 8 + h0] = E0;
            Es[m * 8 + h0 + 1] = E1;
            gs0 += 1.f / (1.f + __expf(-Em[8 + h0]));
            gs1 += 1.f / (1.f + __expf(-Em[9 + h0]));
        }
    }
    // gate-sum wave reduction -> gsum_sh[h]
#pragma unroll
    for (int off = 32; off; off >>= 1) {
        gs0 += __shfl_xor(gs0, off, 64);
        gs1 += __shfl_xor(gs1, off, 64);
    }
    if (l == 0) { gsum_sh[2 * wq] = gs0; gsum_sh[2 * wq + 1] = gs1; }
    __syncthreads();

    // overlays in est (free after score pass)
    float* pmax = est;
    float* psum = est + 256;
    float* vpart = est + 512;
    float* vfin = est + 768;
    float* npart = est + 832;

    const int h8 = t & 7, g32 = t >> 3;
    {
        float vm = -1e30f;
#pragma unroll 4
        for (int i = 0; i < 16; ++i) vm = fmaxf(vm, Es[(g32 + 32 * i) * 8 + h8]);
        pmax[g32 * 8 + h8] = vm;
    }
    __syncthreads();
    if (t < 8) {
        float m_ = pmax[t];
        for (int g = 1; g < 32; ++g) m_ = fmaxf(m_, pmax[g * 8 + t]);
        mx[t] = m_;
        centr[t] = log1pf(gsum_sh[t]);
    }
    __syncthreads();
    {
        const float mh = mx[h8];
        float ss = 0.f;
#pragma unroll 4
        for (int i = 0; i < 16; ++i) ss += __expf(Es[(g32 + 32 * i) * 8 + h8] - mh);
        psum[g32 * 8 + h8] = ss;
    }
    __syncthreads();
    if (t < 8) {
        float s_ = 0.f;
        for (int g = 0; g < 32; ++g) s_ += psum[g * 8 + t];
        invden[t] = 1.f / s_;
    }
    __syncthreads();
    // ---- PV: thread=(h,k), wave = m-group of 128; V reads 256B-coalesced, L2-hot ----
    {
        const int k = t & 7, hh = (t >> 3) & 7;
        const float mh = mx[hh];
        const float* vb = qkv + (size_t)(b * NN) * 192 + 128 + hh * 8 + k;
        float acc = 0.f;
#pragma unroll 4
        for (int i = 0; i < 128; ++i) {
            const int m = w * 128 + i;
            const float a = __expf(Es[m * 8 + hh] - mh);
            acc = fmaf(a, vb[(size_t)m * 192], acc);
        }
        vpart[t] = acc;
    }
    __syncthreads();
    if (t < 64) {
        const int hh = t >> 3;
        vfin[t] = (vpart[t] + vpart[64 + t] + vpart[128 + t] + vpart[192 + t]) * invden[hh] * centr[hh];
    }
    __syncthreads();
    // ---- n_out = vfin @ On ----
    {
        float acc = 0.f;
#pragma unroll
        for (int i = w * 16; i < w * 16 + 16; ++i)
            acc = fmaf(vfin[i], On[i * 64 + l], acc);
        npart[t] = acc;
    }
    __syncthreads();
    if (t < 64) {
        n_out[(size_t)bn * 64 + t] = npart[t] + npart[64 + t] + npart[128 + t] + npart[192 + t];
    }
    // ---- e_out = Es @ Oe, float4 stores ----
    {
        const int j4 = l & 15, mr = l >> 4;
        float oc[8][4];
#pragma unroll
        for (int h = 0; h < 8; ++h) {
            const float4 v = reinterpret_cast<const float4*>(Oe + h * 64 + j4 * 4)[0];
            oc[h][0] = v.x; oc[h][1] = v.y; oc[h][2] = v.z; oc[h][3] = v.w;
        }
        float* eob = e_out + (size_t)bn * 512 * 64;
#pragma unroll 2
        for (int p = 0; p < 32; ++p) {
            const int m = w * 128 + p * 4 + mr;
            const float* er = Es + m * 8;
            const float4 ra = reinterpret_cast<const float4*>(er)[0];
            const float4 rb = reinterpret_cast<const float4*>(er)[1];
            float o0 = ra.x * oc[0][0], o1 = ra.x * oc[0][1], o2 = ra.x * oc[0][2], o3 = ra.x * oc[0][3];
            o0 = fmaf(ra.y, oc[1][0], o0); o1 = fmaf(ra.y, oc[1][1], o1); o2 = fmaf(ra.y, oc[1][2], o2); o3 = fmaf(ra.y, oc[1][3], o3);
            o0 = fmaf(ra.z, oc[2][0], o0); o1 = fmaf(ra.z, oc[2][1], o1); o2 = fmaf(ra.z, oc[2][2], o2); o3 = fmaf(ra.z, oc[2][3], o3);
            o0 = fmaf(ra.w, oc[3][0], o0); o1 = fmaf(ra.w, oc[3][1], o1); o2 = fmaf(ra.w, oc[3][2], o2); o3 = fmaf(ra.w, oc[3][3], o3);
            o0 = fmaf(rb.x, oc[4][0], o0); o1 = fmaf(rb.x, oc[4][1], o1); o2 = fmaf(rb.x, oc[4][2], o2); o3 = fmaf(rb.x, oc[4][3], o3);
            o0 = fmaf(rb.y, oc[5][0], o0); o1 = fmaf(rb.y, oc[5][1], o1); o2 = fmaf(rb.y, oc[5][2], o2); o3 = fmaf(rb.y, oc[5][3], o3);
            o0 = fmaf(rb.z, oc[6][0], o0); o1 = fmaf(rb.z, oc[6][1], o1); o2 = fmaf(rb.z, oc[6][2], o2); o3 = fmaf(rb.z, oc[6][3], o3);
            o0 = fmaf(rb.w, oc[7][0], o0); o1 = fmaf(rb.w, oc[7][1], o1); o2 = fmaf(rb.w, oc[7][2], o2); o3 = fmaf(rb.w, oc[7][3], o3);
            const float4 ov = make_float4(o0, o1, o2, o3);
            reinterpret_cast<float4*>(eob + (size_t)m * 64 + j4 * 4)[0] = ov;
        }
    }
}

extern "C" void kernel_launch(void* const* d_in, const int* in_sizes, int n_in,
                              void* d_out, int out_size, void* d_ws, size_t ws_size,
                              hipStream_t stream) {
    const float* n_in_p = (const float*)d_in[0];
    const float* e_p    = (const float*)d_in[1];
    const float* Wqkv   = (const float*)d_in[2];
    const float* On     = (const float*)d_in[3];
    const float* Wg     = (const float*)d_in[4];
    const float* We     = (const float*)d_in[5];
    const float* Oe     = (const float*)d_in[6];
    float* out = (float*)d_out;
    float* n_out = out;                              // 4*512*64
    float* e_out = out + (size_t)4 * 512 * 64;       // 4*512*512*64
    float* qkv = (float*)d_ws;                       // 4*512*192 floats

    hipLaunchKernelGGL(qkv_proj, dim3(4 * NN), dim3(64), 0, stream, n_in_p, Wqkv, qkv);
    hipLaunchKernelGGL(edge_fused, dim3(4 * NN), dim3(256), 0, stream,
                       e_p, qkv, We, Wg, Oe, On, n_out, e_out);
}

// Round 3
// 263.083 us; speedup vs baseline: 1.9525x; 1.9525x over previous
//
#include <hip/hip_runtime.h>

#define NN 512
#define SCALE 0.35355339059327373f  /* dk^-0.5, dk=8 */

// ---------------- K1: QKV projection ----------------
__global__ __launch_bounds__(64) void qkv_proj(const float* __restrict__ nin,
                                               const float* __restrict__ Wqkv,
                                               float* __restrict__ qkv) {
    const int r = blockIdx.x;   // b*512+n
    const int j = threadIdx.x;  // 0..63
    const float* nr = nin + (size_t)r * 64;
    float a0 = 0.f, a1 = 0.f, a2 = 0.f;
#pragma unroll
    for (int d = 0; d < 64; ++d) {
        const float nv = nr[d];                 // block-uniform -> s_load
        const float* wr = Wqkv + d * 192;
        a0 = fmaf(nv, wr[j], a0);
        a1 = fmaf(nv, wr[64 + j], a1);
        a2 = fmaf(nv, wr[128 + j], a2);
    }
    float* o = qkv + (size_t)r * 192;
    o[j] = a0; o[64 + j] = a1; o[128 + j] = a2;
}

// ---------------- K2: per-edge scores (_E) + gate sums ----------------
// block = (b,n) row. Lane owns edge m (2 per thread). No LDS tiles, no hot barriers.
// _E row (512*8 f32 = 16 KB) is stashed at the head of this row's e_out region.
__global__ __launch_bounds__(256) void edge_score(
    const float* __restrict__ e,
    const float* __restrict__ qkv,
    const float* __restrict__ We,   // (64,8)
    const float* __restrict__ Wg,   // (64,8)
    float* __restrict__ e_out,      // (B,N,N,64) — row head reused as _E stash
    float* __restrict__ gsum_ws)    // (B*N, 8)
{
    const int t = threadIdx.x;
    const int bn = blockIdx.x;
    const int b = bn >> 9;
    const float* Q = qkv + (size_t)bn * 192;          // block-uniform -> s_load
    const float* eb = e + (size_t)bn * 512 * 64;
    float* Erow = e_out + (size_t)bn * 32768;

    float gs[8];
#pragma unroll
    for (int j = 0; j < 8; ++j) gs[j] = 0.f;

#pragma unroll
    for (int half = 0; half < 2; ++half) {
        const int m = t + half * 256;
        const float4* e4 = reinterpret_cast<const float4*>(eb + (size_t)m * 64);
        const float4* k4 = reinterpret_cast<const float4*>(qkv + (size_t)(b * NN + m) * 192 + 64);
        float ee[8], gg[8], ar[8];
#pragma unroll
        for (int j = 0; j < 8; ++j) { ee[j] = 0.f; gg[j] = 0.f; ar[j] = 0.f; }
#pragma unroll 2
        for (int u = 0; u < 16; ++u) {                // d-chunk of 4
            const float4 ev = e4[u];
            const float4 kv = k4[u];
            const float* wE = We + u * 32;            // uniform -> s_load
            const float* wG = Wg + u * 32;
            const float* qp = Q + u * 4;
            const float ec[4] = {ev.x, ev.y, ev.z, ev.w};
            const float kc[4] = {kv.x, kv.y, kv.z, kv.w};
#pragma unroll
            for (int c = 0; c < 4; ++c) {
#pragma unroll
                for (int j = 0; j < 8; ++j) {
                    ee[j] = fmaf(ec[c], wE[c * 8 + j], ee[j]);
                    gg[j] = fmaf(ec[c], wG[c * 8 + j], gg[j]);
                }
                ar[(u * 4 + c) >> 3] = fmaf(kc[c], qp[c], ar[(u * 4 + c) >> 3]);
            }
        }
        float Eh[8];
#pragma unroll
        for (int j = 0; j < 8; ++j) {
            const float a = fminf(fmaxf(ar[j] * SCALE, -5.f), 5.f);
            Eh[j] = a + ee[j];
            gs[j] += 1.f / (1.f + __expf(-gg[j]));
        }
        float4* dst = reinterpret_cast<float4*>(Erow + (size_t)m * 8);
        dst[0] = make_float4(Eh[0], Eh[1], Eh[2], Eh[3]);
        dst[1] = make_float4(Eh[4], Eh[5], Eh[6], Eh[7]);
    }
    // block-reduce gs[8] over 256 threads -> gsum_ws[bn][8]
    __shared__ float gred[4][8];
#pragma unroll
    for (int off = 1; off < 64; off <<= 1)
#pragma unroll
        for (int j = 0; j < 8; ++j) gs[j] += __shfl_xor(gs[j], off, 64);
    if ((t & 63) == 0)
#pragma unroll
        for (int j = 0; j < 8; ++j) gred[t >> 6][j] = gs[j];
    __syncthreads();
    if (t < 8) gsum_ws[(size_t)bn * 8 + t] = gred[0][t] + gred[1][t] + gred[2][t] + gred[3][t];
}

// ---------------- K3: softmax + PV + n_out + e_out ----------------
__global__ __launch_bounds__(256) void edge_out(
    const float* __restrict__ qkv,
    const float* __restrict__ gsum_ws,
    const float* __restrict__ Oe,   // (8,64)
    const float* __restrict__ On,   // (64,64)
    float* __restrict__ n_out,      // (B,N,64)
    float* __restrict__ e_out)      // (B,N,N,64)
{
    __shared__ float Es[NN * 8];    // 16 KB
    __shared__ float pmax[256], psum[256], vpart[256], npart[256];
    __shared__ float vfin[64];
    __shared__ float mx[8], invden[8], centr[8];

    const int t = threadIdx.x;
    const int w = t >> 6;
    const int l = t & 63;
    const int bn = blockIdx.x;
    const int b = bn >> 9;
    float* erow = e_out + (size_t)bn * 32768;

    // load _E row (written by K2 at this row's head) into LDS
    {
        const float4* src = reinterpret_cast<const float4*>(erow);
        float4* dst = reinterpret_cast<float4*>(Es);
#pragma unroll
        for (int i = 0; i < 4; ++i) dst[t + 256 * i] = src[t + 256 * i];
    }
    __syncthreads();

    const int h8 = t & 7, g32 = t >> 3;
    {
        float vm = -1e30f;
#pragma unroll 4
        for (int i = 0; i < 16; ++i) vm = fmaxf(vm, Es[(g32 + 32 * i) * 8 + h8]);
        pmax[g32 * 8 + h8] = vm;
    }
    __syncthreads();
    if (t < 8) {
        float m_ = pmax[t];
        for (int g = 1; g < 32; ++g) m_ = fmaxf(m_, pmax[g * 8 + t]);
        mx[t] = m_;
        centr[t] = log1pf(gsum_ws[(size_t)bn * 8 + t]);
    }
    __syncthreads();
    {
        const float mh = mx[h8];
        float ss = 0.f;
#pragma unroll 4
        for (int i = 0; i < 16; ++i) ss += __expf(Es[(g32 + 32 * i) * 8 + h8] - mh);
        psum[g32 * 8 + h8] = ss;
    }
    __syncthreads();
    if (t < 8) {
        float s_ = 0.f;
        for (int g = 0; g < 32; ++g) s_ += psum[g * 8 + t];
        invden[t] = 1.f / s_;
    }
    __syncthreads();
    // PV: thread=(h,k), wave = m-group of 128; V rows are L2-hot
    {
        const int k = t & 7, hh = (t >> 3) & 7;
        const float mh = mx[hh];
        const float* vb = qkv + (size_t)(b * NN) * 192 + 128 + hh * 8 + k;
        float acc = 0.f;
#pragma unroll 4
        for (int i = 0; i < 128; ++i) {
            const int m = w * 128 + i;
            const float a = __expf(Es[m * 8 + hh] - mh);
            acc = fmaf(a, vb[(size_t)m * 192], acc);
        }
        vpart[t] = acc;
    }
    __syncthreads();
    if (t < 64) {
        const int hh = t >> 3;
        vfin[t] = (vpart[t] + vpart[64 + t] + vpart[128 + t] + vpart[192 + t]) * invden[hh] * centr[hh];
    }
    __syncthreads();
    // n_out = vfin @ On
    {
        float acc = 0.f;
#pragma unroll
        for (int i = w * 16; i < w * 16 + 16; ++i)
            acc = fmaf(vfin[i], On[i * 64 + l], acc);
        npart[t] = acc;
    }
    __syncthreads();
    if (t < 64) {
        n_out[(size_t)bn * 64 + t] = npart[t] + npart[64 + t] + npart[128 + t] + npart[192 + t];
    }
    // e_out = Es @ Oe, float4 stores (overwrites the _E stash last)
    {
        const int j4 = l & 15, mr = l >> 4;
        float oc[8][4];
#pragma unroll
        for (int h = 0; h < 8; ++h) {
            const float4 v = reinterpret_cast<const float4*>(Oe + h * 64 + j4 * 4)[0];
            oc[h][0] = v.x; oc[h][1] = v.y; oc[h][2] = v.z; oc[h][3] = v.w;
        }
#pragma unroll 2
        for (int p = 0; p < 32; ++p) {
            const int m = w * 128 + p * 4 + mr;
            const float* er = Es + m * 8;
            const float4 ra = reinterpret_cast<const float4*>(er)[0];
            const float4 rb = reinterpret_cast<const float4*>(er)[1];
            float o0 = ra.x * oc[0][0], o1 = ra.x * oc[0][1], o2 = ra.x * oc[0][2], o3 = ra.x * oc[0][3];
            o0 = fmaf(ra.y, oc[1][0], o0); o1 = fmaf(ra.y, oc[1][1], o1); o2 = fmaf(ra.y, oc[1][2], o2); o3 = fmaf(ra.y, oc[1][3], o3);
            o0 = fmaf(ra.z, oc[2][0], o0); o1 = fmaf(ra.z, oc[2][1], o1); o2 = fmaf(ra.z, oc[2][2], o2); o3 = fmaf(ra.z, oc[2][3], o3);
            o0 = fmaf(ra.w, oc[3][0], o0); o1 = fmaf(ra.w, oc[3][1], o1); o2 = fmaf(ra.w, oc[3][2], o2); o3 = fmaf(ra.w, oc[3][3], o3);
            o0 = fmaf(rb.x, oc[4][0], o0); o1 = fmaf(rb.x, oc[4][1], o1); o2 = fmaf(rb.x, oc[4][2], o2); o3 = fmaf(rb.x, oc[4][3], o3);
            o0 = fmaf(rb.y, oc[5][0], o0); o1 = fmaf(rb.y, oc[5][1], o1); o2 = fmaf(rb.y, oc[5][2], o2); o3 = fmaf(rb.y, oc[5][3], o3);
            o0 = fmaf(rb.z, oc[6][0], o0); o1 = fmaf(rb.z, oc[6][1], o1); o2 = fmaf(rb.z, oc[6][2], o2); o3 = fmaf(rb.z, oc[6][3], o3);
            o0 = fmaf(rb.w, oc[7][0], o0); o1 = fmaf(rb.w, oc[7][1], o1); o2 = fmaf(rb.w, oc[7][2], o2); o3 = fmaf(rb.w, oc[7][3], o3);
            reinterpret_cast<float4*>(erow + (size_t)m * 64 + j4 * 4)[0] = make_float4(o0, o1, o2, o3);
        }
    }
}

extern "C" void kernel_launch(void* const* d_in, const int* in_sizes, int n_in,
                              void* d_out, int out_size, void* d_ws, size_t ws_size,
                              hipStream_t stream) {
    const float* n_in_p = (const float*)d_in[0];
    const float* e_p    = (const float*)d_in[1];
    const float* Wqkv   = (const float*)d_in[2];
    const float* On     = (const float*)d_in[3];
    const float* Wg     = (const float*)d_in[4];
    const float* We     = (const float*)d_in[5];
    const float* Oe     = (const float*)d_in[6];
    float* out = (float*)d_out;
    float* n_out = out;                              // 4*512*64
    float* e_out = out + (size_t)4 * 512 * 64;       // 4*512*512*64
    float* qkv = (float*)d_ws;                       // 4*512*192 floats
    float* gsum_ws = qkv + (size_t)4 * NN * 192;     // 4*512*8 floats

    hipLaunchKernelGGL(qkv_proj, dim3(4 * NN), dim3(64), 0, stream, n_in_p, Wqkv, qkv);
    hipLaunchKernelGGL(edge_score, dim3(4 * NN), dim3(256), 0, stream,
                       e_p, qkv, We, Wg, e_out, gsum_ws);
    hipLaunchKernelGGL(edge_out, dim3(4 * NN), dim3(256), 0, stream,
                       qkv, gsum_ws, Oe, On, n_out, e_out);
}